// Round 6
// baseline (974.137 us; speedup 1.0000x reference)
//
#include <hip/hip_runtime.h>
#include <hip/hip_bf16.h>
#include <stdint.h>

// NeuralFSM as integer FSM (exact). R5b (R5 + compile fix: __hip_atomic_fence
// -> __threadfence):
//  - p3: LDS-staged bucket scatter -> coalesced global writes (kills the
//    64-lines-per-store pattern; R4 wrote 62-98MB for 25.6MB payload).
//  - ONE persistent mega-kernel for all 20 iterations: 500 blocks x 512 thr,
//    ~60KB LDS (2 blocks/CU, 500<=512 slots -> co-residency guaranteed).
//    Bucket edges live in LDS across iterations (zero per-iter edge traffic);
//    manual device-scope grid barrier (monotonic counter + fences) between
//    iterations. Bin-sort by src>>8 at load time (p4 deleted) for gather
//    locality. Output one-hot written by the same kernel.

#define NN 100000
#define EE 6400000
#define NCHARS 2048
#define ITERS 20
#define NB_NODE 391       // ceil(NN/256)

#define NBKT 500          // dst buckets
#define NPB 200           // nodes per bucket
#define CEDGE 12800       // edges per chunk (stage fits 64KB LDS)
#define NCHUNK 500        // CEDGE*NCHUNK == EE
#define CAPM 13824        // per-bucket LDS edge cap (mean 12800, +9 sigma)

// ---------- decode inputs + zero grid barrier ----------
__global__ void decode_kernel(const float* __restrict__ s0,
                              const float* __restrict__ T,
                              uint8_t* __restrict__ state,
                              uint8_t* __restrict__ nextT,
                              uint32_t* __restrict__ bar) {
    int i = blockIdx.x * blockDim.x + threadIdx.x;
    if (blockIdx.x == 0 && threadIdx.x < 64) bar[threadIdx.x] = 0u;
    if (i < NCHARS) {
        const float* row = T + i * 8;
        int t = 0;
        #pragma unroll
        for (int k = 1; k < 8; ++k) if (row[k] > 0.5f) t = k;
        nextT[i] = (uint8_t)t;
    }
    if (i < NN) {
        const float* row = s0 + i * 8;
        int s = 0;
        #pragma unroll
        for (int k = 1; k < 8; ++k) if (row[k] > 0.5f) s = k;
        state[i] = (uint8_t)s;
    }
}

// ---------- P1: per-chunk bucket histogram ----------
__global__ void __launch_bounds__(512) p1_hist(const int* __restrict__ dst,
                                               uint32_t* __restrict__ hist) {
    __shared__ uint32_t cnt[NBKT];
    int t = threadIdx.x;
    int c = blockIdx.x;
    for (int i = t; i < NBKT; i += 512) cnt[i] = 0;
    __syncthreads();
    int e0 = c * CEDGE;
    for (int i = t; i < CEDGE; i += 512) atomicAdd(&cnt[dst[e0 + i] / NPB], 1u);
    __syncthreads();
    for (int i = t; i < NBKT; i += 512) hist[(size_t)c * NBKT + i] = cnt[i];
}

// ---------- P2a: per-bucket exclusive scan over chunks ----------
__global__ void p2a_scan(uint32_t* __restrict__ hist, uint32_t* __restrict__ total) {
    __shared__ uint32_t lds[256];
    int t = threadIdx.x;
    int b = blockIdx.x;
    uint32_t carry = 0;
    for (int c0 = 0; c0 < NCHUNK; c0 += 256) {
        int c = c0 + t;
        uint32_t v = (c < NCHUNK) ? hist[(size_t)c * NBKT + b] : 0u;
        lds[t] = v;
        __syncthreads();
        for (int off = 1; off < 256; off <<= 1) {
            uint32_t x = (t >= off) ? lds[t - off] : 0u;
            __syncthreads();
            lds[t] += x;
            __syncthreads();
        }
        if (c < NCHUNK) hist[(size_t)c * NBKT + b] = lds[t] - v + carry;
        uint32_t tot = lds[255];
        __syncthreads();
        carry += tot;
    }
    if (t == 0) total[b] = carry;
}

// ---------- P2b: scan bucket totals ----------
__global__ void p2b_scan(const uint32_t* __restrict__ total,
                         uint32_t* __restrict__ bucket_base) {
    __shared__ uint32_t lds[512];
    int t = threadIdx.x;
    uint32_t v = (t < NBKT) ? total[t] : 0u;
    lds[t] = v;
    __syncthreads();
    for (int off = 1; off < 512; off <<= 1) {
        uint32_t x = (t >= off) ? lds[t - off] : 0u;
        __syncthreads();
        lds[t] += x;
        __syncthreads();
    }
    if (t < NBKT) bucket_base[t] = lds[t] - v;
    if (t == 511) bucket_base[NBKT] = lds[511];   // == EE
}

// ---------- P3: LDS-staged partition -> coalesced writes ----------
__global__ void __launch_bounds__(512) p3_partition(const int* __restrict__ src,
                                                    const int* __restrict__ dst,
                                                    const uint32_t* __restrict__ hist,
                                                    const uint32_t* __restrict__ bucket_base,
                                                    uint32_t* __restrict__ csr) {
    __shared__ uint32_t stage[CEDGE];       // 51.2 KB
    __shared__ uint32_t loc[NBKT + 1];
    __shared__ uint32_t cur[NBKT];          // cursor, then segoff
    __shared__ uint32_t scanb[512];
    int t = threadIdx.x;
    int c = blockIdx.x;
    int e0 = c * CEDGE;
    for (int i = t; i < NBKT; i += 512) cur[i] = 0;
    __syncthreads();
    for (int i = t; i < CEDGE; i += 512) atomicAdd(&cur[dst[e0 + i] / NPB], 1u);
    __syncthreads();
    uint32_t v = (t < NBKT) ? cur[t] : 0u;
    scanb[t] = v;
    __syncthreads();
    for (int off = 1; off < 512; off <<= 1) {
        uint32_t x = (t >= off) ? scanb[t - off] : 0u;
        __syncthreads();
        scanb[t] += x;
        __syncthreads();
    }
    if (t < NBKT) { loc[t] = scanb[t] - v; cur[t] = scanb[t] - v; }
    if (t == 0) loc[NBKT] = CEDGE;
    __syncthreads();
    for (int i = t; i < CEDGE; i += 512) {
        int d = dst[e0 + i];
        int s = src[e0 + i];
        int bb = d / NPB;
        uint32_t dl = (uint32_t)(d - bb * NPB);          // < 200
        uint32_t pos = atomicAdd(&cur[bb], 1u);
        stage[pos] = ((uint32_t)s << 8) | dl;            // 25 bits total
    }
    __syncthreads();
    if (t < NBKT) cur[t] = bucket_base[t] + hist[(size_t)c * NBKT + t] - loc[t];  // segoff
    __syncthreads();
    for (int i = t; i < CEDGE; i += 512) {
        int lo = 0, hi = NBKT;                            // loc[lo] <= i < loc[lo+1]
        while (hi - lo > 1) { int mid = (lo + hi) >> 1; if (loc[mid] <= (uint32_t)i) lo = mid; else hi = mid; }
        csr[cur[lo] + (uint32_t)i] = stage[i];            // consecutive i -> consecutive addr
    }
}

// ---------- mega: load+sort bucket into LDS, 20 iters with grid barrier ----------
__global__ void __launch_bounds__(512, 4) mega_kernel(const uint32_t* __restrict__ csr,
                                                      const uint32_t* __restrict__ bucket_base,
                                                      uint8_t* __restrict__ sA,
                                                      uint8_t* __restrict__ sB,
                                                      const uint8_t* __restrict__ nextT,
                                                      float* __restrict__ out,
                                                      uint32_t* __restrict__ bar) {
    __shared__ uint32_t eL[CAPM];           // 55.3 KB
    __shared__ uint32_t binh[512];
    __shared__ uint32_t mask[256];
    __shared__ uint8_t  nT[NCHARS];
    __shared__ uint8_t  sown[256];
    int t = threadIdx.x;
    int b = blockIdx.x;
    uint32_t base = bucket_base[b];
    int n = (int)(bucket_base[b + 1] - base);
    int nl = n < CAPM ? n : CAPM;

    ((uint32_t*)nT)[t] = ((const uint32_t*)nextT)[t];     // 512*4 == 2048
    if (t < NPB) sown[t] = sA[b * NPB + t];
    binh[t] = 0;
    __syncthreads();
    if (n <= CAPM) {
        for (int i = t; i < n; i += 512) atomicAdd(&binh[csr[base + i] >> 16], 1u);  // src>>8
        __syncthreads();
        uint32_t v = binh[t];
        __syncthreads();
        for (int off = 1; off < 512; off <<= 1) {
            uint32_t x = (t >= off) ? binh[t - off] : 0u;
            __syncthreads();
            binh[t] += x;
            __syncthreads();
        }
        uint32_t excl = binh[t] - v;
        __syncthreads();
        binh[t] = excl;
        __syncthreads();
        for (int i = t; i < n; i += 512) {
            uint32_t w = csr[base + i];
            uint32_t pos = atomicAdd(&binh[w >> 16], 1u);
            eL[pos] = w;
        }
    } else {
        for (int i = t; i < nl; i += 512) eL[i] = csr[base + i];   // unsorted, tail from global
    }
    __syncthreads();

    for (int p = 0; p < ITERS; ++p) {
        const uint8_t* sc = (p & 1) ? sB : sA;
        uint8_t*       sn = (p & 1) ? sA : sB;
        if (t < 256) mask[t] = 0;
        __syncthreads();
        for (int i = t; i < nl; i += 512) {
            uint32_t w = eL[i];
            uint32_t s = sc[w >> 8];
            atomicOr(&mask[w & 255u], 1u << s);
        }
        for (int i = CAPM + t; i < n; i += 512) {          // overflow tail (normally empty)
            uint32_t w = csr[base + i];
            uint32_t s = sc[w >> 8];
            atomicOr(&mask[w & 255u], 1u << s);
        }
        __syncthreads();
        if (t < NPB) {
            uint8_t ns = nT[(mask[t] << 3) + sown[t]];
            sown[t] = ns;
            if (p < ITERS - 1) sn[b * NPB + t] = ns;       // others need it next iter
        }
        if (p < ITERS - 1) {
            __syncthreads();
            if (t == 0) {
                __threadfence();                            // release: flush to device scope
                atomicAdd(bar, 1u);
                uint32_t target = (uint32_t)(p + 1) * NBKT;
                while (__hip_atomic_load(bar, __ATOMIC_RELAXED, __HIP_MEMORY_SCOPE_AGENT) < target)
                    __builtin_amdgcn_s_sleep(8);
                __threadfence();                            // acquire side
            }
            __syncthreads();
        }
    }
    __syncthreads();
    // one-hot output: 200 nodes * 8 floats, coalesced
    for (int f = t; f < NPB * 8; f += 512) {
        int node = f >> 3;
        out[(size_t)b * (NPB * 8) + f] = ((f & 7) == (int)sown[node]) ? 1.f : 0.f;
    }
}

// ---------- fallback (tiny ws): R1 mask/atomicOr path ----------
__global__ void fb_init(uint32_t* __restrict__ mask) {
    int i = blockIdx.x * blockDim.x + threadIdx.x;
    if (i < NN) mask[i] = 0u;
}
__global__ void fb_edge(const int* __restrict__ src, const int* __restrict__ dst,
                        const uint8_t* __restrict__ state, uint32_t* __restrict__ mask) {
    int i = blockIdx.x * blockDim.x + threadIdx.x;
    int stride = gridDim.x * blockDim.x;
    for (int e = i; e < EE; e += stride) atomicOr(&mask[dst[e]], 1u << state[src[e]]);
}
__global__ void fb_update(uint8_t* __restrict__ state, uint32_t* __restrict__ mask,
                          const uint8_t* __restrict__ nextT) {
    int i = blockIdx.x * blockDim.x + threadIdx.x;
    if (i < NN) {
        uint32_t m = mask[i];
        state[i] = nextT[(m << 3) + state[i]];
        mask[i] = 0u;
    }
}
__global__ void fb_output(const uint8_t* __restrict__ state, float* __restrict__ out) {
    int i = blockIdx.x * blockDim.x + threadIdx.x;
    if (i < NN) {
        int s = state[i];
        float4 lo = make_float4(s == 0 ? 1.f : 0.f, s == 1 ? 1.f : 0.f,
                                s == 2 ? 1.f : 0.f, s == 3 ? 1.f : 0.f);
        float4 hi = make_float4(s == 4 ? 1.f : 0.f, s == 5 ? 1.f : 0.f,
                                s == 6 ? 1.f : 0.f, s == 7 ? 1.f : 0.f);
        float4* o = (float4*)(out + (size_t)i * 8);
        o[0] = lo;
        o[1] = hi;
    }
}

extern "C" void kernel_launch(void* const* d_in, const int* in_sizes, int n_in,
                              void* d_out, int out_size, void* d_ws, size_t ws_size,
                              hipStream_t stream) {
    const float* s0  = (const float*)d_in[0];
    const int*   ei  = (const int*)d_in[1];   // [2,E]: row0=src, row1=dst
    const float* T   = (const float*)d_in[2];
    float*       out = (float*)d_out;
    const int* src = ei;
    const int* dst = ei + EE;

    uint8_t* basep = (uint8_t*)d_ws;
    size_t off = 0;
    auto alloc = [&](size_t sz) -> void* {
        void* p = basep + off;
        off += (sz + 255) & ~(size_t)255;
        return p;
    };
    uint32_t* csr         = (uint32_t*)alloc(sizeof(uint32_t) * EE);
    uint32_t* hist        = (uint32_t*)alloc(sizeof(uint32_t) * (size_t)NCHUNK * NBKT);
    uint32_t* total       = (uint32_t*)alloc(sizeof(uint32_t) * NBKT);
    uint32_t* bucket_base = (uint32_t*)alloc(sizeof(uint32_t) * (NBKT + 1));
    uint8_t*  nextT       = (uint8_t*)alloc(NCHARS);
    uint8_t*  stateA      = (uint8_t*)alloc(NN);
    uint8_t*  stateB      = (uint8_t*)alloc(NN);
    uint32_t* bar         = (uint32_t*)alloc(sizeof(uint32_t) * 64);
    bool have_ws = (off <= ws_size);

    if (have_ws) {
        decode_kernel<<<NB_NODE, 256, 0, stream>>>(s0, T, stateA, nextT, bar);
        p1_hist<<<NCHUNK, 512, 0, stream>>>(dst, hist);
        p2a_scan<<<NBKT, 256, 0, stream>>>(hist, total);
        p2b_scan<<<1, 512, 0, stream>>>(total, bucket_base);
        p3_partition<<<NCHUNK, 512, 0, stream>>>(src, dst, hist, bucket_base, csr);
        mega_kernel<<<NBKT, 512, 0, stream>>>(csr, bucket_base, stateA, stateB,
                                              nextT, out, bar);
    } else {
        uint32_t* mask = (uint32_t*)d_ws;           // < 1 MB path
        uint8_t*  nT   = (uint8_t*)d_ws + 400128;
        uint8_t*  st   = (uint8_t*)d_ws + 402432;
        uint32_t* br   = (uint32_t*)((uint8_t*)d_ws + 503040);
        decode_kernel<<<NB_NODE, 256, 0, stream>>>(s0, T, st, nT, br);
        fb_init<<<NB_NODE, 256, 0, stream>>>(mask);
        for (int it = 0; it < ITERS; ++it) {
            fb_edge<<<2048, 256, 0, stream>>>(src, dst, st, mask);
            fb_update<<<NB_NODE, 256, 0, stream>>>(st, mask, nT);
        }
        fb_output<<<NB_NODE, 256, 0, stream>>>(st, out);
    }
}

// Round 7
// 610.367 us; speedup vs baseline: 1.5960x; 1.5960x over previous
//
#include <hip/hip_runtime.h>
#include <hip/hip_bf16.h>
#include <stdint.h>

// NeuralFSM as integer FSM (exact). R7 = R5b with the grid barrier fixed and
// the gather unrolled:
//  - R6 counters: mega 855us, HBM 0.4%, VALU 2.6% -> ~34us per grid barrier
//    (500 blocks polling+adding ONE line at agent scope = self-congestion).
//  - Barrier v2: two-level arrival (50 lines x 10 blocks -> 1 top counter),
//    fan-out release over 50 lines, <=10 pollers/line, s_sleep backoff.
//  - Gather unrolled x8: 8 independent L2 byte-gathers in flight per thread
//    (R6 had a serial load->atomic dependence chain, 9us/iter).
//  - Fence protocol unchanged from R6 (proved absmax=0): __syncthreads, then
//    thread0 __threadfence (L2 writeback covers blockmates on same XCD),
//    arrive, poll, __threadfence, __syncthreads.

#define NN 100000
#define EE 6400000
#define NCHARS 2048
#define ITERS 20
#define NB_NODE 391       // ceil(NN/256)

#define NBKT 500          // dst buckets
#define NPB 200           // nodes per bucket
#define CEDGE 12800       // edges per chunk (stage fits 64KB LDS)
#define NCHUNK 500        // CEDGE*NCHUNK == EE
#define CAPM 13824        // per-bucket LDS edge cap (mean 12800, +9 sigma)

// barrier layout in words (each line 64B apart)
#define BLINES 50         // arrival lines (10 blocks each)
#define BAR_ARR(i) ((i) * 16)
#define BAR_TOP    800
#define BAR_REL(i) (832 + (i) * 16)
#define BAR_WORDS  2048   // 8KB zeroed by decode

// ---------- decode inputs + zero barrier region ----------
__global__ void decode_kernel(const float* __restrict__ s0,
                              const float* __restrict__ T,
                              uint8_t* __restrict__ state,
                              uint8_t* __restrict__ nextT,
                              uint32_t* __restrict__ bar) {
    int i = blockIdx.x * blockDim.x + threadIdx.x;
    if (blockIdx.x == 0)
        for (int j = threadIdx.x; j < BAR_WORDS; j += 256) bar[j] = 0u;
    if (i < NCHARS) {
        const float* row = T + i * 8;
        int t = 0;
        #pragma unroll
        for (int k = 1; k < 8; ++k) if (row[k] > 0.5f) t = k;
        nextT[i] = (uint8_t)t;
    }
    if (i < NN) {
        const float* row = s0 + i * 8;
        int s = 0;
        #pragma unroll
        for (int k = 1; k < 8; ++k) if (row[k] > 0.5f) s = k;
        state[i] = (uint8_t)s;
    }
}

// ---------- P1: per-chunk bucket histogram ----------
__global__ void __launch_bounds__(512) p1_hist(const int* __restrict__ dst,
                                               uint32_t* __restrict__ hist) {
    __shared__ uint32_t cnt[NBKT];
    int t = threadIdx.x;
    int c = blockIdx.x;
    for (int i = t; i < NBKT; i += 512) cnt[i] = 0;
    __syncthreads();
    int e0 = c * CEDGE;
    for (int i = t; i < CEDGE; i += 512) atomicAdd(&cnt[dst[e0 + i] / NPB], 1u);
    __syncthreads();
    for (int i = t; i < NBKT; i += 512) hist[(size_t)c * NBKT + i] = cnt[i];
}

// ---------- P2a: per-bucket exclusive scan over chunks ----------
__global__ void p2a_scan(uint32_t* __restrict__ hist, uint32_t* __restrict__ total) {
    __shared__ uint32_t lds[256];
    int t = threadIdx.x;
    int b = blockIdx.x;
    uint32_t carry = 0;
    for (int c0 = 0; c0 < NCHUNK; c0 += 256) {
        int c = c0 + t;
        uint32_t v = (c < NCHUNK) ? hist[(size_t)c * NBKT + b] : 0u;
        lds[t] = v;
        __syncthreads();
        for (int off = 1; off < 256; off <<= 1) {
            uint32_t x = (t >= off) ? lds[t - off] : 0u;
            __syncthreads();
            lds[t] += x;
            __syncthreads();
        }
        if (c < NCHUNK) hist[(size_t)c * NBKT + b] = lds[t] - v + carry;
        uint32_t tot = lds[255];
        __syncthreads();
        carry += tot;
    }
    if (t == 0) total[b] = carry;
}

// ---------- P2b: scan bucket totals ----------
__global__ void p2b_scan(const uint32_t* __restrict__ total,
                         uint32_t* __restrict__ bucket_base) {
    __shared__ uint32_t lds[512];
    int t = threadIdx.x;
    uint32_t v = (t < NBKT) ? total[t] : 0u;
    lds[t] = v;
    __syncthreads();
    for (int off = 1; off < 512; off <<= 1) {
        uint32_t x = (t >= off) ? lds[t - off] : 0u;
        __syncthreads();
        lds[t] += x;
        __syncthreads();
    }
    if (t < NBKT) bucket_base[t] = lds[t] - v;
    if (t == 511) bucket_base[NBKT] = lds[511];   // == EE
}

// ---------- P3: LDS-staged partition -> coalesced writes ----------
__global__ void __launch_bounds__(512) p3_partition(const int* __restrict__ src,
                                                    const int* __restrict__ dst,
                                                    const uint32_t* __restrict__ hist,
                                                    const uint32_t* __restrict__ bucket_base,
                                                    uint32_t* __restrict__ csr) {
    __shared__ uint32_t stage[CEDGE];       // 51.2 KB
    __shared__ uint32_t loc[NBKT + 1];
    __shared__ uint32_t cur[NBKT];          // cursor, then segoff
    __shared__ uint32_t scanb[512];
    int t = threadIdx.x;
    int c = blockIdx.x;
    int e0 = c * CEDGE;
    for (int i = t; i < NBKT; i += 512) cur[i] = 0;
    __syncthreads();
    for (int i = t; i < CEDGE; i += 512) atomicAdd(&cur[dst[e0 + i] / NPB], 1u);
    __syncthreads();
    uint32_t v = (t < NBKT) ? cur[t] : 0u;
    scanb[t] = v;
    __syncthreads();
    for (int off = 1; off < 512; off <<= 1) {
        uint32_t x = (t >= off) ? scanb[t - off] : 0u;
        __syncthreads();
        scanb[t] += x;
        __syncthreads();
    }
    if (t < NBKT) { loc[t] = scanb[t] - v; cur[t] = scanb[t] - v; }
    if (t == 0) loc[NBKT] = CEDGE;
    __syncthreads();
    for (int i = t; i < CEDGE; i += 512) {
        int d = dst[e0 + i];
        int s = src[e0 + i];
        int bb = d / NPB;
        uint32_t dl = (uint32_t)(d - bb * NPB);          // < 200
        uint32_t pos = atomicAdd(&cur[bb], 1u);
        stage[pos] = ((uint32_t)s << 8) | dl;            // 25 bits total
    }
    __syncthreads();
    if (t < NBKT) cur[t] = bucket_base[t] + hist[(size_t)c * NBKT + t] - loc[t];  // segoff
    __syncthreads();
    for (int i = t; i < CEDGE; i += 512) {
        int lo = 0, hi = NBKT;                            // loc[lo] <= i < loc[lo+1]
        while (hi - lo > 1) { int mid = (lo + hi) >> 1; if (loc[mid] <= (uint32_t)i) lo = mid; else hi = mid; }
        csr[cur[lo] + (uint32_t)i] = stage[i];            // consecutive i -> consecutive addr
    }
}

// ---------- mega: load+sort bucket into LDS, 20 iters with grid barrier ----------
__global__ void __launch_bounds__(512, 4) mega_kernel(const uint32_t* __restrict__ csr,
                                                      const uint32_t* __restrict__ bucket_base,
                                                      uint8_t* __restrict__ sA,
                                                      uint8_t* __restrict__ sB,
                                                      const uint8_t* __restrict__ nextT,
                                                      float* __restrict__ out,
                                                      uint32_t* __restrict__ bar) {
    __shared__ uint32_t eL[CAPM];           // 55.3 KB
    __shared__ uint32_t binh[512];
    __shared__ uint32_t mask[256];
    __shared__ uint8_t  nT[NCHARS];
    __shared__ uint8_t  sown[256];
    int t = threadIdx.x;
    int b = blockIdx.x;
    uint32_t base = bucket_base[b];
    int n = (int)(bucket_base[b + 1] - base);
    int nl = n < CAPM ? n : CAPM;

    ((uint32_t*)nT)[t] = ((const uint32_t*)nextT)[t];     // 512*4 == 2048
    if (t < NPB) sown[t] = sA[b * NPB + t];
    binh[t] = 0;
    __syncthreads();
    if (n <= CAPM) {
        for (int i = t; i < n; i += 512) atomicAdd(&binh[csr[base + i] >> 16], 1u);  // src>>8
        __syncthreads();
        uint32_t v = binh[t];
        __syncthreads();
        for (int off = 1; off < 512; off <<= 1) {
            uint32_t x = (t >= off) ? binh[t - off] : 0u;
            __syncthreads();
            binh[t] += x;
            __syncthreads();
        }
        uint32_t excl = binh[t] - v;
        __syncthreads();
        binh[t] = excl;
        __syncthreads();
        for (int i = t; i < n; i += 512) {
            uint32_t w = csr[base + i];
            uint32_t pos = atomicAdd(&binh[w >> 16], 1u);
            eL[pos] = w;
        }
    } else {
        for (int i = t; i < nl; i += 512) eL[i] = csr[base + i];   // unsorted, tail from global
    }
    __syncthreads();

    const int line = b % BLINES;
    for (int p = 0; p < ITERS; ++p) {
        const uint8_t* sc = (p & 1) ? sB : sA;
        uint8_t*       sn = (p & 1) ? sA : sB;
        if (t < 256) mask[t] = 0;
        __syncthreads();
        // unroll x8: 8 independent L2 byte-gathers in flight
        int i = t;
        for (; i + 7 * 512 < nl; i += 8 * 512) {
            uint32_t w0 = eL[i +    0], w1 = eL[i +  512], w2 = eL[i + 1024], w3 = eL[i + 1536];
            uint32_t w4 = eL[i + 2048], w5 = eL[i + 2560], w6 = eL[i + 3072], w7 = eL[i + 3584];
            uint32_t m0 = 1u << sc[w0 >> 8], m1 = 1u << sc[w1 >> 8];
            uint32_t m2 = 1u << sc[w2 >> 8], m3 = 1u << sc[w3 >> 8];
            uint32_t m4 = 1u << sc[w4 >> 8], m5 = 1u << sc[w5 >> 8];
            uint32_t m6 = 1u << sc[w6 >> 8], m7 = 1u << sc[w7 >> 8];
            atomicOr(&mask[w0 & 255u], m0);
            atomicOr(&mask[w1 & 255u], m1);
            atomicOr(&mask[w2 & 255u], m2);
            atomicOr(&mask[w3 & 255u], m3);
            atomicOr(&mask[w4 & 255u], m4);
            atomicOr(&mask[w5 & 255u], m5);
            atomicOr(&mask[w6 & 255u], m6);
            atomicOr(&mask[w7 & 255u], m7);
        }
        for (; i < nl; i += 512) {
            uint32_t w = eL[i];
            atomicOr(&mask[w & 255u], 1u << sc[w >> 8]);
        }
        for (int j = CAPM + t; j < n; j += 512) {          // overflow tail (normally empty)
            uint32_t w = csr[base + j];
            atomicOr(&mask[w & 255u], 1u << sc[w >> 8]);
        }
        __syncthreads();
        if (t < NPB) {
            uint8_t ns = nT[(mask[t] << 3) + sown[t]];
            sown[t] = ns;
            if (p < ITERS - 1) sn[b * NPB + t] = ns;       // others need it next iter
        }
        if (p < ITERS - 1) {
            __syncthreads();
            if (t == 0) {
                __threadfence();                           // L2 writeback: release
                uint32_t epoch = (uint32_t)(p + 1);
                uint32_t old = atomicAdd(&bar[BAR_ARR(line)], 1u);
                if (old + 1u == 10u * epoch) {             // group complete
                    uint32_t told = atomicAdd(&bar[BAR_TOP], 1u);
                    if (told + 1u == (uint32_t)BLINES * epoch) {   // all arrived
                        for (int r = 0; r < BLINES; ++r)
                            atomicExch(&bar[BAR_REL(r)], epoch);   // fan-out release
                    }
                }
                while (__hip_atomic_load(&bar[BAR_REL(line)], __ATOMIC_RELAXED,
                                         __HIP_MEMORY_SCOPE_AGENT) < epoch)
                    __builtin_amdgcn_s_sleep(16);
                __threadfence();                           // acquire side
            }
            __syncthreads();
        }
    }
    __syncthreads();
    // one-hot output: 200 nodes * 8 floats, coalesced
    for (int f = t; f < NPB * 8; f += 512) {
        int node = f >> 3;
        out[(size_t)b * (NPB * 8) + f] = ((f & 7) == (int)sown[node]) ? 1.f : 0.f;
    }
}

// ---------- fallback (tiny ws): R1 mask/atomicOr path ----------
__global__ void fb_init(uint32_t* __restrict__ mask) {
    int i = blockIdx.x * blockDim.x + threadIdx.x;
    if (i < NN) mask[i] = 0u;
}
__global__ void fb_edge(const int* __restrict__ src, const int* __restrict__ dst,
                        const uint8_t* __restrict__ state, uint32_t* __restrict__ mask) {
    int i = blockIdx.x * blockDim.x + threadIdx.x;
    int stride = gridDim.x * blockDim.x;
    for (int e = i; e < EE; e += stride) atomicOr(&mask[dst[e]], 1u << state[src[e]]);
}
__global__ void fb_update(uint8_t* __restrict__ state, uint32_t* __restrict__ mask,
                          const uint8_t* __restrict__ nextT) {
    int i = blockIdx.x * blockDim.x + threadIdx.x;
    if (i < NN) {
        uint32_t m = mask[i];
        state[i] = nextT[(m << 3) + state[i]];
        mask[i] = 0u;
    }
}
__global__ void fb_output(const uint8_t* __restrict__ state, float* __restrict__ out) {
    int i = blockIdx.x * blockDim.x + threadIdx.x;
    if (i < NN) {
        int s = state[i];
        float4 lo = make_float4(s == 0 ? 1.f : 0.f, s == 1 ? 1.f : 0.f,
                                s == 2 ? 1.f : 0.f, s == 3 ? 1.f : 0.f);
        float4 hi = make_float4(s == 4 ? 1.f : 0.f, s == 5 ? 1.f : 0.f,
                                s == 6 ? 1.f : 0.f, s == 7 ? 1.f : 0.f);
        float4* o = (float4*)(out + (size_t)i * 8);
        o[0] = lo;
        o[1] = hi;
    }
}

extern "C" void kernel_launch(void* const* d_in, const int* in_sizes, int n_in,
                              void* d_out, int out_size, void* d_ws, size_t ws_size,
                              hipStream_t stream) {
    const float* s0  = (const float*)d_in[0];
    const int*   ei  = (const int*)d_in[1];   // [2,E]: row0=src, row1=dst
    const float* T   = (const float*)d_in[2];
    float*       out = (float*)d_out;
    const int* src = ei;
    const int* dst = ei + EE;

    uint8_t* basep = (uint8_t*)d_ws;
    size_t off = 0;
    auto alloc = [&](size_t sz) -> void* {
        void* p = basep + off;
        off += (sz + 255) & ~(size_t)255;
        return p;
    };
    uint32_t* csr         = (uint32_t*)alloc(sizeof(uint32_t) * EE);
    uint32_t* hist        = (uint32_t*)alloc(sizeof(uint32_t) * (size_t)NCHUNK * NBKT);
    uint32_t* total       = (uint32_t*)alloc(sizeof(uint32_t) * NBKT);
    uint32_t* bucket_base = (uint32_t*)alloc(sizeof(uint32_t) * (NBKT + 1));
    uint8_t*  nextT       = (uint8_t*)alloc(NCHARS);
    uint8_t*  stateA      = (uint8_t*)alloc(NN);
    uint8_t*  stateB      = (uint8_t*)alloc(NN);
    uint32_t* bar         = (uint32_t*)alloc(sizeof(uint32_t) * BAR_WORDS);
    bool have_ws = (off <= ws_size);

    if (have_ws) {
        decode_kernel<<<NB_NODE, 256, 0, stream>>>(s0, T, stateA, nextT, bar);
        p1_hist<<<NCHUNK, 512, 0, stream>>>(dst, hist);
        p2a_scan<<<NBKT, 256, 0, stream>>>(hist, total);
        p2b_scan<<<1, 512, 0, stream>>>(total, bucket_base);
        p3_partition<<<NCHUNK, 512, 0, stream>>>(src, dst, hist, bucket_base, csr);
        mega_kernel<<<NBKT, 512, 0, stream>>>(csr, bucket_base, stateA, stateB,
                                              nextT, out, bar);
    } else {
        uint32_t* mask = (uint32_t*)d_ws;           // < 1 MB path
        uint8_t*  nT   = (uint8_t*)d_ws + 400128;
        uint8_t*  st   = (uint8_t*)d_ws + 402432;
        uint32_t* br   = (uint32_t*)((uint8_t*)d_ws + 503040);
        decode_kernel<<<NB_NODE, 256, 0, stream>>>(s0, T, st, nT, br);
        fb_init<<<NB_NODE, 256, 0, stream>>>(mask);
        for (int it = 0; it < ITERS; ++it) {
            fb_edge<<<2048, 256, 0, stream>>>(src, dst, st, mask);
            fb_update<<<NB_NODE, 256, 0, stream>>>(st, mask, nT);
        }
        fb_output<<<NB_NODE, 256, 0, stream>>>(st, out);
    }
}

// Round 8
// 397.176 us; speedup vs baseline: 2.4527x; 1.5368x over previous
//
#include <hip/hip_runtime.h>
#include <hip/hip_bf16.h>
#include <stdint.h>

// NeuralFSM as integer FSM (exact). R8: fence-free persistent iteration.
//  - R7 post-mortem: ~14us/epoch attributed to __threadfence lowering to
//    buffer_wbl2+buffer_inv (L2 writeback/invalidate), ~63 ops/XCD/epoch.
//  - R8 moves ALL cross-block state through coherence-point accesses:
//    state is nibble-packed (100000 nodes -> 12500 words, 50KB); every block
//    reloads it into LDS each iter via relaxed AGENT-scope atomic loads
//    (stride-1, coalesced, bypass stale L1/L2); blocks write their own 25
//    packed words via agent-scope atomic stores. No fences anywhere.
//  - Barrier: two-level tree (50 lines x 10 blocks -> top -> fan-out),
//    relaxed atomics only; __syncthreads' vmcnt(0) drain orders the state
//    stores before the arrival add.
//  - Edges stream from global csr each iter (L2-resident, stride-1) -> no
//    eL in LDS, no bin-sort (gathers now hit LDS), no overflow path.

#define NN 100000
#define EE 6400000
#define NCHARS 2048
#define ITERS 20
#define NB_NODE 391       // ceil(NN/256)

#define NBKT 500          // dst buckets == persistent blocks
#define NPB 200           // nodes per bucket (25 packed words each)
#define WPS 12500         // words of packed state (NN/8)
#define CEDGE 12800       // edges per chunk in build
#define NCHUNK 500        // CEDGE*NCHUNK == EE

// barrier layout in words (each line 64B apart)
#define BLINES 50         // arrival lines (10 blocks each)
#define BAR_ARR(i) ((i) * 16)
#define BAR_TOP    800
#define BAR_REL(i) (832 + (i) * 16)
#define BAR_WORDS  2048   // 8KB

// ---------- init: zero barrier + packed state ----------
__global__ void init_kernel(uint32_t* __restrict__ bar, uint32_t* __restrict__ gPk0) {
    int i = blockIdx.x * blockDim.x + threadIdx.x;
    int stride = gridDim.x * blockDim.x;
    for (int j = i; j < BAR_WORDS; j += stride) bar[j] = 0u;
    for (int j = i; j < WPS; j += stride) gPk0[j] = 0u;
}

// ---------- decode: nextT table + initial nibble-packed state ----------
__global__ void decode_kernel(const float* __restrict__ s0,
                              const float* __restrict__ T,
                              uint32_t* __restrict__ gPk0,
                              uint8_t* __restrict__ nextT) {
    int i = blockIdx.x * blockDim.x + threadIdx.x;
    if (i < NCHARS) {
        const float* row = T + i * 8;
        int t = 0;
        #pragma unroll
        for (int k = 1; k < 8; ++k) if (row[k] > 0.5f) t = k;
        nextT[i] = (uint8_t)t;
    }
    if (i < NN) {
        const float* row = s0 + i * 8;
        int s = 0;
        #pragma unroll
        for (int k = 1; k < 8; ++k) if (row[k] > 0.5f) s = k;
        atomicOr(&gPk0[i >> 3], (uint32_t)s << ((i & 7) << 2));
    }
}

// ---------- P1: per-chunk bucket histogram ----------
__global__ void __launch_bounds__(512) p1_hist(const int* __restrict__ dst,
                                               uint32_t* __restrict__ hist) {
    __shared__ uint32_t cnt[NBKT];
    int t = threadIdx.x;
    int c = blockIdx.x;
    for (int i = t; i < NBKT; i += 512) cnt[i] = 0;
    __syncthreads();
    int e0 = c * CEDGE;
    for (int i = t; i < CEDGE; i += 512) atomicAdd(&cnt[dst[e0 + i] / NPB], 1u);
    __syncthreads();
    for (int i = t; i < NBKT; i += 512) hist[(size_t)c * NBKT + i] = cnt[i];
}

// ---------- P2a: per-bucket exclusive scan over chunks ----------
__global__ void p2a_scan(uint32_t* __restrict__ hist, uint32_t* __restrict__ total) {
    __shared__ uint32_t lds[256];
    int t = threadIdx.x;
    int b = blockIdx.x;
    uint32_t carry = 0;
    for (int c0 = 0; c0 < NCHUNK; c0 += 256) {
        int c = c0 + t;
        uint32_t v = (c < NCHUNK) ? hist[(size_t)c * NBKT + b] : 0u;
        lds[t] = v;
        __syncthreads();
        for (int off = 1; off < 256; off <<= 1) {
            uint32_t x = (t >= off) ? lds[t - off] : 0u;
            __syncthreads();
            lds[t] += x;
            __syncthreads();
        }
        if (c < NCHUNK) hist[(size_t)c * NBKT + b] = lds[t] - v + carry;
        uint32_t tot = lds[255];
        __syncthreads();
        carry += tot;
    }
    if (t == 0) total[b] = carry;
}

// ---------- P2b: scan bucket totals ----------
__global__ void p2b_scan(const uint32_t* __restrict__ total,
                         uint32_t* __restrict__ bucket_base) {
    __shared__ uint32_t lds[512];
    int t = threadIdx.x;
    uint32_t v = (t < NBKT) ? total[t] : 0u;
    lds[t] = v;
    __syncthreads();
    for (int off = 1; off < 512; off <<= 1) {
        uint32_t x = (t >= off) ? lds[t - off] : 0u;
        __syncthreads();
        lds[t] += x;
        __syncthreads();
    }
    if (t < NBKT) bucket_base[t] = lds[t] - v;
    if (t == 511) bucket_base[NBKT] = lds[511];   // == EE
}

// ---------- P3: LDS-staged partition -> coalesced writes ----------
__global__ void __launch_bounds__(512) p3_partition(const int* __restrict__ src,
                                                    const int* __restrict__ dst,
                                                    const uint32_t* __restrict__ hist,
                                                    const uint32_t* __restrict__ bucket_base,
                                                    uint32_t* __restrict__ csr) {
    __shared__ uint32_t stage[CEDGE];       // 51.2 KB
    __shared__ uint32_t loc[NBKT + 1];
    __shared__ uint32_t cur[NBKT];          // cursor, then segoff
    __shared__ uint32_t scanb[512];
    int t = threadIdx.x;
    int c = blockIdx.x;
    int e0 = c * CEDGE;
    for (int i = t; i < NBKT; i += 512) cur[i] = 0;
    __syncthreads();
    for (int i = t; i < CEDGE; i += 512) atomicAdd(&cur[dst[e0 + i] / NPB], 1u);
    __syncthreads();
    uint32_t v = (t < NBKT) ? cur[t] : 0u;
    scanb[t] = v;
    __syncthreads();
    for (int off = 1; off < 512; off <<= 1) {
        uint32_t x = (t >= off) ? scanb[t - off] : 0u;
        __syncthreads();
        scanb[t] += x;
        __syncthreads();
    }
    if (t < NBKT) { loc[t] = scanb[t] - v; cur[t] = scanb[t] - v; }
    if (t == 0) loc[NBKT] = CEDGE;
    __syncthreads();
    for (int i = t; i < CEDGE; i += 512) {
        int d = dst[e0 + i];
        int s = src[e0 + i];
        int bb = d / NPB;
        uint32_t dl = (uint32_t)(d - bb * NPB);          // < 200
        uint32_t pos = atomicAdd(&cur[bb], 1u);
        stage[pos] = ((uint32_t)s << 8) | dl;            // 25 bits total
    }
    __syncthreads();
    if (t < NBKT) cur[t] = bucket_base[t] + hist[(size_t)c * NBKT + t] - loc[t];  // segoff
    __syncthreads();
    for (int i = t; i < CEDGE; i += 512) {
        int lo = 0, hi = NBKT;                            // loc[lo] <= i < loc[lo+1]
        while (hi - lo > 1) { int mid = (lo + hi) >> 1; if (loc[mid] <= (uint32_t)i) lo = mid; else hi = mid; }
        csr[cur[lo] + (uint32_t)i] = stage[i];            // consecutive i -> consecutive addr
    }
}

// ---------- mega: fence-free persistent 20 iterations ----------
__global__ void __launch_bounds__(512, 4) mega_kernel(const uint32_t* __restrict__ csr,
                                                      const uint32_t* __restrict__ bucket_base,
                                                      uint32_t* __restrict__ gPkA,
                                                      uint32_t* __restrict__ gPkB,
                                                      const uint8_t* __restrict__ nextT,
                                                      float* __restrict__ out,
                                                      uint32_t* __restrict__ bar) {
    __shared__ uint32_t sPk[WPS];           // 50 KB packed state
    __shared__ uint32_t mask[256];
    __shared__ uint32_t packOwn[32];
    __shared__ uint8_t  nT[NCHARS];
    __shared__ uint8_t  sown[256];
    int t = threadIdx.x;
    int b = blockIdx.x;
    uint32_t base = bucket_base[b];
    uint32_t end  = bucket_base[b + 1];

    ((uint32_t*)nT)[t] = ((const uint32_t*)nextT)[t];     // 512*4 == 2048
    const int line = b % BLINES;

    for (int p = 0; p < ITERS; ++p) {
        const uint32_t* curG = (p & 1) ? gPkB : gPkA;
        uint32_t*       nxtG = (p & 1) ? gPkA : gPkB;
        // reload full packed state coherently (bypasses stale L1/L2)
        for (int i = t; i < WPS; i += 512)
            sPk[i] = __hip_atomic_load(&curG[i], __ATOMIC_RELAXED, __HIP_MEMORY_SCOPE_AGENT);
        if (t < 256) mask[t] = 0;
        if (t < 32) packOwn[t] = 0;
        __syncthreads();

        // gather: stream edges from global (L2-resident), state from LDS
        uint32_t e = base + t;
        for (; e + 1536 < end; e += 2048) {
            uint32_t w0 = csr[e], w1 = csr[e + 512], w2 = csr[e + 1024], w3 = csr[e + 1536];
            uint32_t s0_ = w0 >> 8, s1_ = w1 >> 8, s2_ = w2 >> 8, s3_ = w3 >> 8;
            uint32_t n0 = (sPk[s0_ >> 3] >> ((s0_ & 7) << 2)) & 7u;
            uint32_t n1 = (sPk[s1_ >> 3] >> ((s1_ & 7) << 2)) & 7u;
            uint32_t n2 = (sPk[s2_ >> 3] >> ((s2_ & 7) << 2)) & 7u;
            uint32_t n3 = (sPk[s3_ >> 3] >> ((s3_ & 7) << 2)) & 7u;
            atomicOr(&mask[w0 & 255u], 1u << n0);
            atomicOr(&mask[w1 & 255u], 1u << n1);
            atomicOr(&mask[w2 & 255u], 1u << n2);
            atomicOr(&mask[w3 & 255u], 1u << n3);
        }
        for (; e < end; e += 512) {
            uint32_t w = csr[e];
            uint32_t s_ = w >> 8;
            uint32_t nb = (sPk[s_ >> 3] >> ((s_ & 7) << 2)) & 7u;
            atomicOr(&mask[w & 255u], 1u << nb);
        }
        __syncthreads();

        // own-node update + nibble pack
        if (t < NPB) {
            int node = b * NPB + t;
            uint32_t sOwn = (sPk[node >> 3] >> ((node & 7) << 2)) & 7u;
            uint8_t ns = nT[(mask[t] << 3) + sOwn];
            sown[t] = ns;
            atomicOr(&packOwn[t >> 3], (uint32_t)ns << ((t & 7) << 2));
        }
        __syncthreads();
        if (t < 25)
            __hip_atomic_store(&nxtG[25 * b + t], packOwn[t],
                               __ATOMIC_RELAXED, __HIP_MEMORY_SCOPE_AGENT);

        if (p < ITERS - 1) {
            __syncthreads();                 // drains vmcnt: stores at coherence point
            if (t == 0) {
                uint32_t epoch = (uint32_t)(p + 1);
                uint32_t old = atomicAdd(&bar[BAR_ARR(line)], 1u);
                if (old + 1u == 10u * epoch) {             // group complete
                    uint32_t told = atomicAdd(&bar[BAR_TOP], 1u);
                    if (told + 1u == (uint32_t)BLINES * epoch) {   // all arrived
                        for (int r = 0; r < BLINES; ++r)
                            atomicExch(&bar[BAR_REL(r)], epoch);   // fan-out release
                    }
                }
                while (__hip_atomic_load(&bar[BAR_REL(line)], __ATOMIC_RELAXED,
                                         __HIP_MEMORY_SCOPE_AGENT) < epoch)
                    __builtin_amdgcn_s_sleep(16);
            }
            __syncthreads();
        }
    }
    __syncthreads();
    // one-hot output: 200 nodes * 8 floats, coalesced
    for (int f = t; f < NPB * 8; f += 512) {
        int node = f >> 3;
        out[(size_t)b * (NPB * 8) + f] = ((f & 7) == (int)sown[node]) ? 1.f : 0.f;
    }
}

// ---------- fallback (tiny ws): R1 mask/atomicOr path ----------
__global__ void fb_decode(const float* __restrict__ s0, const float* __restrict__ T,
                          uint8_t* __restrict__ state, uint8_t* __restrict__ nextT,
                          uint32_t* __restrict__ mask) {
    int i = blockIdx.x * blockDim.x + threadIdx.x;
    if (i < NCHARS) {
        const float* row = T + i * 8;
        int t = 0;
        #pragma unroll
        for (int k = 1; k < 8; ++k) if (row[k] > 0.5f) t = k;
        nextT[i] = (uint8_t)t;
    }
    if (i < NN) {
        const float* row = s0 + i * 8;
        int s = 0;
        #pragma unroll
        for (int k = 1; k < 8; ++k) if (row[k] > 0.5f) s = k;
        state[i] = (uint8_t)s;
        mask[i] = 0u;
    }
}
__global__ void fb_edge(const int* __restrict__ src, const int* __restrict__ dst,
                        const uint8_t* __restrict__ state, uint32_t* __restrict__ mask) {
    int i = blockIdx.x * blockDim.x + threadIdx.x;
    int stride = gridDim.x * blockDim.x;
    for (int e = i; e < EE; e += stride) atomicOr(&mask[dst[e]], 1u << state[src[e]]);
}
__global__ void fb_update(uint8_t* __restrict__ state, uint32_t* __restrict__ mask,
                          const uint8_t* __restrict__ nextT) {
    int i = blockIdx.x * blockDim.x + threadIdx.x;
    if (i < NN) {
        uint32_t m = mask[i];
        state[i] = nextT[(m << 3) + state[i]];
        mask[i] = 0u;
    }
}
__global__ void fb_output(const uint8_t* __restrict__ state, float* __restrict__ out) {
    int i = blockIdx.x * blockDim.x + threadIdx.x;
    if (i < NN) {
        int s = state[i];
        float4 lo = make_float4(s == 0 ? 1.f : 0.f, s == 1 ? 1.f : 0.f,
                                s == 2 ? 1.f : 0.f, s == 3 ? 1.f : 0.f);
        float4 hi = make_float4(s == 4 ? 1.f : 0.f, s == 5 ? 1.f : 0.f,
                                s == 6 ? 1.f : 0.f, s == 7 ? 1.f : 0.f);
        float4* o = (float4*)(out + (size_t)i * 8);
        o[0] = lo;
        o[1] = hi;
    }
}

extern "C" void kernel_launch(void* const* d_in, const int* in_sizes, int n_in,
                              void* d_out, int out_size, void* d_ws, size_t ws_size,
                              hipStream_t stream) {
    const float* s0  = (const float*)d_in[0];
    const int*   ei  = (const int*)d_in[1];   // [2,E]: row0=src, row1=dst
    const float* T   = (const float*)d_in[2];
    float*       out = (float*)d_out;
    const int* src = ei;
    const int* dst = ei + EE;

    uint8_t* basep = (uint8_t*)d_ws;
    size_t off = 0;
    auto alloc = [&](size_t sz) -> void* {
        void* p = basep + off;
        off += (sz + 255) & ~(size_t)255;
        return p;
    };
    uint32_t* csr         = (uint32_t*)alloc(sizeof(uint32_t) * EE);
    uint32_t* hist        = (uint32_t*)alloc(sizeof(uint32_t) * (size_t)NCHUNK * NBKT);
    uint32_t* total       = (uint32_t*)alloc(sizeof(uint32_t) * NBKT);
    uint32_t* bucket_base = (uint32_t*)alloc(sizeof(uint32_t) * (NBKT + 1));
    uint8_t*  nextT       = (uint8_t*)alloc(NCHARS);
    uint32_t* gPkA        = (uint32_t*)alloc(sizeof(uint32_t) * WPS);
    uint32_t* gPkB        = (uint32_t*)alloc(sizeof(uint32_t) * WPS);
    uint32_t* bar         = (uint32_t*)alloc(sizeof(uint32_t) * BAR_WORDS);
    bool have_ws = (off <= ws_size);

    if (have_ws) {
        init_kernel<<<58, 256, 0, stream>>>(bar, gPkA);
        decode_kernel<<<NB_NODE, 256, 0, stream>>>(s0, T, gPkA, nextT);
        p1_hist<<<NCHUNK, 512, 0, stream>>>(dst, hist);
        p2a_scan<<<NBKT, 256, 0, stream>>>(hist, total);
        p2b_scan<<<1, 512, 0, stream>>>(total, bucket_base);
        p3_partition<<<NCHUNK, 512, 0, stream>>>(src, dst, hist, bucket_base, csr);
        mega_kernel<<<NBKT, 512, 0, stream>>>(csr, bucket_base, gPkA, gPkB,
                                              nextT, out, bar);
    } else {
        uint32_t* mask = (uint32_t*)d_ws;           // < 1 MB path
        uint8_t*  nT   = (uint8_t*)d_ws + 400128;
        uint8_t*  st   = (uint8_t*)d_ws + 402432;
        fb_decode<<<NB_NODE, 256, 0, stream>>>(s0, T, st, nT, mask);
        for (int it = 0; it < ITERS; ++it) {
            fb_edge<<<2048, 256, 0, stream>>>(src, dst, st, mask);
            fb_update<<<NB_NODE, 256, 0, stream>>>(st, mask, nT);
        }
        fb_output<<<NB_NODE, 256, 0, stream>>>(st, out);
    }
}

// Round 9
// 305.724 us; speedup vs baseline: 3.1863x; 1.2991x over previous
//
#include <hip/hip_runtime.h>
#include <hip/hip_bf16.h>
#include <stdint.h>

// NeuralFSM as integer FSM (exact). R9:
//  - 250 persistent blocks x 1024 thr (400 nodes, ~25.6K edges each):
//    halves the per-epoch state-reload volume (25MB -> 12.5MB) and barrier size.
//  - Reload via inline-asm global_load_dwordx4 sc1 (agent-scope coherent,
//    4x wider than R8's scalar __hip_atomic_load; per-word coherence is all
//    we need since producers write whole words).
//  - p4_sortsrc build pass: bin-sort each bucket's edges by src>>8 ->
//    consecutive lanes gather neighboring sPk words (R8 had 2.08e7 LDS
//    bank-conflict cycles from random nibble gathers).
//  - Edges packed (src<<9)|dst_local9 (26 bits), stream from L2 (~3.2MB/XCD).
//  - Fence-free coherent exchange + 2-level relaxed-atomic barrier as R8.

#define NN 100000
#define EE 6400000
#define NCHARS 2048
#define ITERS 20
#define NB_NODE 391       // ceil(NN/256)

#define NBKT 250          // dst buckets == persistent blocks
#define NPB 400           // nodes per bucket (50 packed words each)
#define WPS 12500         // words of packed state (NN/8)
#define X4N 3125          // WPS/4
#define CEDGE 12800       // edges per chunk in build
#define NCHUNK 500        // CEDGE*NCHUNK == EE
#define PCAP 13312        // p4 half-bucket LDS stage cap

// barrier layout in words (each line 64B apart)
#define BLINES 25         // arrival lines (10 blocks each)
#define BAR_ARR(i) ((i) * 16)
#define BAR_TOP    800
#define BAR_REL(i) (832 + (i) * 16)
#define BAR_WORDS  2048   // 8KB

typedef uint32_t u32x4 __attribute__((ext_vector_type(4)));

// ---------- init: zero barrier + packed state ----------
__global__ void init_kernel(uint32_t* __restrict__ bar, uint32_t* __restrict__ gPk0) {
    int i = blockIdx.x * blockDim.x + threadIdx.x;
    int stride = gridDim.x * blockDim.x;
    for (int j = i; j < BAR_WORDS; j += stride) bar[j] = 0u;
    for (int j = i; j < WPS; j += stride) gPk0[j] = 0u;
}

// ---------- decode: nextT table + initial nibble-packed state ----------
__global__ void decode_kernel(const float* __restrict__ s0,
                              const float* __restrict__ T,
                              uint32_t* __restrict__ gPk0,
                              uint8_t* __restrict__ nextT) {
    int i = blockIdx.x * blockDim.x + threadIdx.x;
    if (i < NCHARS) {
        const float* row = T + i * 8;
        int t = 0;
        #pragma unroll
        for (int k = 1; k < 8; ++k) if (row[k] > 0.5f) t = k;
        nextT[i] = (uint8_t)t;
    }
    if (i < NN) {
        const float* row = s0 + i * 8;
        int s = 0;
        #pragma unroll
        for (int k = 1; k < 8; ++k) if (row[k] > 0.5f) s = k;
        atomicOr(&gPk0[i >> 3], (uint32_t)s << ((i & 7) << 2));
    }
}

// ---------- P1: per-chunk bucket histogram ----------
__global__ void __launch_bounds__(512) p1_hist(const int* __restrict__ dst,
                                               uint32_t* __restrict__ hist) {
    __shared__ uint32_t cnt[NBKT];
    int t = threadIdx.x;
    int c = blockIdx.x;
    for (int i = t; i < NBKT; i += 512) cnt[i] = 0;
    __syncthreads();
    int e0 = c * CEDGE;
    for (int i = t; i < CEDGE; i += 512) atomicAdd(&cnt[dst[e0 + i] / NPB], 1u);
    __syncthreads();
    for (int i = t; i < NBKT; i += 512) hist[(size_t)c * NBKT + i] = cnt[i];
}

// ---------- P2a: per-bucket exclusive scan over chunks ----------
__global__ void p2a_scan(uint32_t* __restrict__ hist, uint32_t* __restrict__ total) {
    __shared__ uint32_t lds[256];
    int t = threadIdx.x;
    int b = blockIdx.x;
    uint32_t carry = 0;
    for (int c0 = 0; c0 < NCHUNK; c0 += 256) {
        int c = c0 + t;
        uint32_t v = (c < NCHUNK) ? hist[(size_t)c * NBKT + b] : 0u;
        lds[t] = v;
        __syncthreads();
        for (int off = 1; off < 256; off <<= 1) {
            uint32_t x = (t >= off) ? lds[t - off] : 0u;
            __syncthreads();
            lds[t] += x;
            __syncthreads();
        }
        if (c < NCHUNK) hist[(size_t)c * NBKT + b] = lds[t] - v + carry;
        uint32_t tot = lds[255];
        __syncthreads();
        carry += tot;
    }
    if (t == 0) total[b] = carry;
}

// ---------- P2b: scan bucket totals ----------
__global__ void p2b_scan(const uint32_t* __restrict__ total,
                         uint32_t* __restrict__ bucket_base) {
    __shared__ uint32_t lds[512];
    int t = threadIdx.x;
    uint32_t v = (t < NBKT) ? total[t] : 0u;
    lds[t] = v;
    __syncthreads();
    for (int off = 1; off < 512; off <<= 1) {
        uint32_t x = (t >= off) ? lds[t - off] : 0u;
        __syncthreads();
        lds[t] += x;
        __syncthreads();
    }
    if (t < NBKT) bucket_base[t] = lds[t] - v;
    if (t == 511) bucket_base[NBKT] = lds[511];   // == EE
}

// ---------- P3: LDS-staged partition -> coalesced writes ----------
__global__ void __launch_bounds__(512) p3_partition(const int* __restrict__ src,
                                                    const int* __restrict__ dst,
                                                    const uint32_t* __restrict__ hist,
                                                    const uint32_t* __restrict__ bucket_base,
                                                    uint32_t* __restrict__ csr) {
    __shared__ uint32_t stage[CEDGE];       // 51.2 KB
    __shared__ uint32_t loc[NBKT + 1];
    __shared__ uint32_t cur[NBKT];          // cursor, then segoff
    __shared__ uint32_t scanb[512];
    int t = threadIdx.x;
    int c = blockIdx.x;
    int e0 = c * CEDGE;
    for (int i = t; i < NBKT; i += 512) cur[i] = 0;
    __syncthreads();
    for (int i = t; i < CEDGE; i += 512) atomicAdd(&cur[dst[e0 + i] / NPB], 1u);
    __syncthreads();
    uint32_t v = (t < NBKT) ? cur[t] : 0u;
    scanb[t] = v;
    __syncthreads();
    for (int off = 1; off < 512; off <<= 1) {
        uint32_t x = (t >= off) ? scanb[t - off] : 0u;
        __syncthreads();
        scanb[t] += x;
        __syncthreads();
    }
    if (t < NBKT) { loc[t] = scanb[t] - v; cur[t] = scanb[t] - v; }
    if (t == 0) loc[NBKT] = CEDGE;
    __syncthreads();
    for (int i = t; i < CEDGE; i += 512) {
        int d = dst[e0 + i];
        int s = src[e0 + i];
        int bb = d / NPB;
        uint32_t dl = (uint32_t)(d - bb * NPB);          // < 400 (9 bits)
        uint32_t pos = atomicAdd(&cur[bb], 1u);
        stage[pos] = ((uint32_t)s << 9) | dl;            // 26 bits total
    }
    __syncthreads();
    if (t < NBKT) cur[t] = bucket_base[t] + hist[(size_t)c * NBKT + t] - loc[t];  // segoff
    __syncthreads();
    for (int i = t; i < CEDGE; i += 512) {
        int lo = 0, hi = NBKT;                            // loc[lo] <= i < loc[lo+1]
        while (hi - lo > 1) { int mid = (lo + hi) >> 1; if (loc[mid] <= (uint32_t)i) lo = mid; else hi = mid; }
        csr[cur[lo] + (uint32_t)i] = stage[i];            // consecutive i -> consecutive addr
    }
}

// ---------- P4: bin-sort each half-bucket by src>>8 (gather locality) ----------
__global__ void __launch_bounds__(512) p4_sortsrc(uint32_t* __restrict__ csr,
                                                  const uint32_t* __restrict__ bucket_base) {
    __shared__ uint32_t st[PCAP];           // 53.2 KB
    __shared__ uint32_t binh[512];
    int t = threadIdx.x;
    int j = blockIdx.x;
    int b = j >> 1, h = j & 1;
    uint32_t base = bucket_base[b], endb = bucket_base[b + 1];
    uint32_t n = endb - base;
    uint32_t n1 = (n + 1) >> 1;
    uint32_t r0 = h ? base + n1 : base;
    uint32_t cnt = h ? n - n1 : n1;
    if (cnt > PCAP) return;                 // leave unsorted (still correct)
    for (uint32_t i = t; i < cnt; i += 512) st[i] = csr[r0 + i];
    binh[t] = 0;
    __syncthreads();
    for (uint32_t i = t; i < cnt; i += 512) atomicAdd(&binh[st[i] >> 17], 1u);  // src>>8
    __syncthreads();
    uint32_t v = binh[t];
    __syncthreads();
    for (int off = 1; off < 512; off <<= 1) {
        uint32_t x = (t >= off) ? binh[t - off] : 0u;
        __syncthreads();
        binh[t] += x;
        __syncthreads();
    }
    uint32_t excl = binh[t] - v;
    __syncthreads();
    binh[t] = excl;                          // becomes cursor
    __syncthreads();
    for (uint32_t i = t; i < cnt; i += 512) {
        uint32_t w = st[i];
        uint32_t pos = atomicAdd(&binh[w >> 17], 1u);
        csr[r0 + pos] = w;
    }
}

// ---------- mega: fence-free persistent 20 iterations ----------
__global__ void __launch_bounds__(1024) mega_kernel(const uint32_t* __restrict__ csr,
                                                    const uint32_t* __restrict__ bucket_base,
                                                    uint32_t* __restrict__ gPkA,
                                                    uint32_t* __restrict__ gPkB,
                                                    const uint8_t* __restrict__ nextT,
                                                    float* __restrict__ out,
                                                    uint32_t* __restrict__ bar) {
    __shared__ uint32_t sPk[WPS];           // 50 KB packed state
    __shared__ uint32_t mask[NPB];          // 1.6 KB
    __shared__ uint32_t packOwn[NPB / 8];
    __shared__ uint8_t  nT[NCHARS];
    __shared__ uint8_t  sown[NPB];
    int t = threadIdx.x;
    int b = blockIdx.x;
    uint32_t base = bucket_base[b];
    uint32_t end  = bucket_base[b + 1];

    if (t < 512) ((uint32_t*)nT)[t] = ((const uint32_t*)nextT)[t];   // 2048 B
    const int line = b % BLINES;

    for (int p = 0; p < ITERS; ++p) {
        const uint32_t* curG = (p & 1) ? gPkB : gPkA;
        uint32_t*       nxtG = (p & 1) ? gPkA : gPkB;
        // coherent x4 reload of full packed state (bypasses stale L1/L2)
        {
            const u32x4* g4 = (const u32x4*)curG;
            int i0 = t, i1 = t + 1024, i2 = t + 2048;
            int i3 = t + 3072; if (i3 > X4N - 1) i3 = X4N - 1;
            const u32x4 *p0 = g4 + i0, *p1 = g4 + i1, *p2 = g4 + i2, *p3 = g4 + i3;
            u32x4 a0, a1, a2, a3;
            asm volatile(
                "global_load_dwordx4 %0, %4, off sc1\n\t"
                "global_load_dwordx4 %1, %5, off sc1\n\t"
                "global_load_dwordx4 %2, %6, off sc1\n\t"
                "global_load_dwordx4 %3, %7, off sc1\n\t"
                "s_waitcnt vmcnt(0)"
                : "=&v"(a0), "=&v"(a1), "=&v"(a2), "=&v"(a3)
                : "v"(p0), "v"(p1), "v"(p2), "v"(p3)
                : "memory");
            u32x4* s4 = (u32x4*)sPk;
            s4[i0] = a0; s4[i1] = a1; s4[i2] = a2; s4[i3] = a3;
        }
        if (t < NPB) mask[t] = 0;
        if (t < NPB / 8) packOwn[t] = 0;
        __syncthreads();

        // gather: edges from global (L2-resident, src-sorted), state from LDS
        uint32_t e = base + t;
        for (; e + 3072 < end; e += 4096) {
            uint32_t w0 = csr[e], w1 = csr[e + 1024], w2 = csr[e + 2048], w3 = csr[e + 3072];
            uint32_t s0_ = w0 >> 9, s1_ = w1 >> 9, s2_ = w2 >> 9, s3_ = w3 >> 9;
            uint32_t n0 = (sPk[s0_ >> 3] >> ((s0_ & 7) << 2)) & 7u;
            uint32_t n1 = (sPk[s1_ >> 3] >> ((s1_ & 7) << 2)) & 7u;
            uint32_t n2 = (sPk[s2_ >> 3] >> ((s2_ & 7) << 2)) & 7u;
            uint32_t n3 = (sPk[s3_ >> 3] >> ((s3_ & 7) << 2)) & 7u;
            atomicOr(&mask[w0 & 511u], 1u << n0);
            atomicOr(&mask[w1 & 511u], 1u << n1);
            atomicOr(&mask[w2 & 511u], 1u << n2);
            atomicOr(&mask[w3 & 511u], 1u << n3);
        }
        for (; e < end; e += 1024) {
            uint32_t w = csr[e];
            uint32_t s_ = w >> 9;
            uint32_t nb = (sPk[s_ >> 3] >> ((s_ & 7) << 2)) & 7u;
            atomicOr(&mask[w & 511u], 1u << nb);
        }
        __syncthreads();

        // own-node update + nibble pack
        if (t < NPB) {
            int node = b * NPB + t;
            uint32_t sOwn = (sPk[node >> 3] >> ((node & 7) << 2)) & 7u;
            uint8_t ns = nT[(mask[t] << 3) + sOwn];
            sown[t] = ns;
            atomicOr(&packOwn[t >> 3], (uint32_t)ns << ((t & 7) << 2));
        }
        __syncthreads();
        if (p < ITERS - 1) {
            if (t < NPB / 8)
                __hip_atomic_store(&nxtG[(NPB / 8) * b + t], packOwn[t],
                                   __ATOMIC_RELAXED, __HIP_MEMORY_SCOPE_AGENT);
            __syncthreads();                 // drains vmcnt: stores at coherence point
            if (t == 0) {
                uint32_t epoch = (uint32_t)(p + 1);
                uint32_t old = atomicAdd(&bar[BAR_ARR(line)], 1u);
                if (old + 1u == 10u * epoch) {             // group complete
                    uint32_t told = atomicAdd(&bar[BAR_TOP], 1u);
                    if (told + 1u == (uint32_t)BLINES * epoch) {   // all arrived
                        for (int r = 0; r < BLINES; ++r)
                            atomicExch(&bar[BAR_REL(r)], epoch);   // fan-out release
                    }
                }
                while (__hip_atomic_load(&bar[BAR_REL(line)], __ATOMIC_RELAXED,
                                         __HIP_MEMORY_SCOPE_AGENT) < epoch)
                    __builtin_amdgcn_s_sleep(16);
            }
            __syncthreads();
        }
    }
    __syncthreads();
    // one-hot output: 400 nodes * 8 floats, coalesced
    for (int f = t; f < NPB * 8; f += 1024) {
        int node = f >> 3;
        out[(size_t)b * (NPB * 8) + f] = ((f & 7) == (int)sown[node]) ? 1.f : 0.f;
    }
}

// ---------- fallback (tiny ws): R1 mask/atomicOr path ----------
__global__ void fb_decode(const float* __restrict__ s0, const float* __restrict__ T,
                          uint8_t* __restrict__ state, uint8_t* __restrict__ nextT,
                          uint32_t* __restrict__ mask) {
    int i = blockIdx.x * blockDim.x + threadIdx.x;
    if (i < NCHARS) {
        const float* row = T + i * 8;
        int t = 0;
        #pragma unroll
        for (int k = 1; k < 8; ++k) if (row[k] > 0.5f) t = k;
        nextT[i] = (uint8_t)t;
    }
    if (i < NN) {
        const float* row = s0 + i * 8;
        int s = 0;
        #pragma unroll
        for (int k = 1; k < 8; ++k) if (row[k] > 0.5f) s = k;
        state[i] = (uint8_t)s;
        mask[i] = 0u;
    }
}
__global__ void fb_edge(const int* __restrict__ src, const int* __restrict__ dst,
                        const uint8_t* __restrict__ state, uint32_t* __restrict__ mask) {
    int i = blockIdx.x * blockDim.x + threadIdx.x;
    int stride = gridDim.x * blockDim.x;
    for (int e = i; e < EE; e += stride) atomicOr(&mask[dst[e]], 1u << state[src[e]]);
}
__global__ void fb_update(uint8_t* __restrict__ state, uint32_t* __restrict__ mask,
                          const uint8_t* __restrict__ nextT) {
    int i = blockIdx.x * blockDim.x + threadIdx.x;
    if (i < NN) {
        uint32_t m = mask[i];
        state[i] = nextT[(m << 3) + state[i]];
        mask[i] = 0u;
    }
}
__global__ void fb_output(const uint8_t* __restrict__ state, float* __restrict__ out) {
    int i = blockIdx.x * blockDim.x + threadIdx.x;
    if (i < NN) {
        int s = state[i];
        float4 lo = make_float4(s == 0 ? 1.f : 0.f, s == 1 ? 1.f : 0.f,
                                s == 2 ? 1.f : 0.f, s == 3 ? 1.f : 0.f);
        float4 hi = make_float4(s == 4 ? 1.f : 0.f, s == 5 ? 1.f : 0.f,
                                s == 6 ? 1.f : 0.f, s == 7 ? 1.f : 0.f);
        float4* o = (float4*)(out + (size_t)i * 8);
        o[0] = lo;
        o[1] = hi;
    }
}

extern "C" void kernel_launch(void* const* d_in, const int* in_sizes, int n_in,
                              void* d_out, int out_size, void* d_ws, size_t ws_size,
                              hipStream_t stream) {
    const float* s0  = (const float*)d_in[0];
    const int*   ei  = (const int*)d_in[1];   // [2,E]: row0=src, row1=dst
    const float* T   = (const float*)d_in[2];
    float*       out = (float*)d_out;
    const int* src = ei;
    const int* dst = ei + EE;

    uint8_t* basep = (uint8_t*)d_ws;
    size_t off = 0;
    auto alloc = [&](size_t sz) -> void* {
        void* p = basep + off;
        off += (sz + 255) & ~(size_t)255;
        return p;
    };
    uint32_t* csr         = (uint32_t*)alloc(sizeof(uint32_t) * EE);
    uint32_t* hist        = (uint32_t*)alloc(sizeof(uint32_t) * (size_t)NCHUNK * NBKT);
    uint32_t* total       = (uint32_t*)alloc(sizeof(uint32_t) * NBKT);
    uint32_t* bucket_base = (uint32_t*)alloc(sizeof(uint32_t) * (NBKT + 1));
    uint8_t*  nextT       = (uint8_t*)alloc(NCHARS);
    uint32_t* gPkA        = (uint32_t*)alloc(sizeof(uint32_t) * WPS);
    uint32_t* gPkB        = (uint32_t*)alloc(sizeof(uint32_t) * WPS);
    uint32_t* bar         = (uint32_t*)alloc(sizeof(uint32_t) * BAR_WORDS);
    bool have_ws = (off <= ws_size);

    if (have_ws) {
        init_kernel<<<58, 256, 0, stream>>>(bar, gPkA);
        decode_kernel<<<NB_NODE, 256, 0, stream>>>(s0, T, gPkA, nextT);
        p1_hist<<<NCHUNK, 512, 0, stream>>>(dst, hist);
        p2a_scan<<<NBKT, 256, 0, stream>>>(hist, total);
        p2b_scan<<<1, 512, 0, stream>>>(total, bucket_base);
        p3_partition<<<NCHUNK, 512, 0, stream>>>(src, dst, hist, bucket_base, csr);
        p4_sortsrc<<<NBKT * 2, 512, 0, stream>>>(csr, bucket_base);
        mega_kernel<<<NBKT, 1024, 0, stream>>>(csr, bucket_base, gPkA, gPkB,
                                               nextT, out, bar);
    } else {
        uint32_t* mask = (uint32_t*)d_ws;           // < 1 MB path
        uint8_t*  nT   = (uint8_t*)d_ws + 400128;
        uint8_t*  st   = (uint8_t*)d_ws + 402432;
        fb_decode<<<NB_NODE, 256, 0, stream>>>(s0, T, st, nT, mask);
        for (int it = 0; it < ITERS; ++it) {
            fb_edge<<<2048, 256, 0, stream>>>(src, dst, st, mask);
            fb_update<<<NB_NODE, 256, 0, stream>>>(st, mask, nT);
        }
        fb_output<<<NB_NODE, 256, 0, stream>>>(st, out);
    }
}

// Round 11
// 284.891 us; speedup vs baseline: 3.4193x; 1.0731x over previous
//
#include <hip/hip_runtime.h>
#include <hip/hip_bf16.h>
#include <stdint.h>

// NeuralFSM as integer FSM (exact). R11 = R10 with the p3 wave-mapping bug
// fixed: count phase and scatter phase MUST assign each edge to the same
// wave (both use int4-group loops). R10's scalar scatter consumed per-wave
// cursor regions sized by the int4-group count -> overruns -> lost edges.
//  - p1: per-wave sub-histograms (8x256) -> ~8x less LDS-atomic contention.
//  - p3: per-(wave,bucket) cursors; both phases int4-grouped.
//  - decode absorbs init (direct packed-word stores).
//  - mega unchanged from R9 (128us; 250 blocks x 1024, coherent x4 reload,
//    fence-free 2-level barrier, src-sorted edges via p4).

#define NN 100000
#define EE 6400000
#define NCHARS 2048
#define ITERS 20

#define NBKT 250          // dst buckets == persistent blocks
#define NPB 400           // nodes per bucket (50 packed words each)
#define WPS 12500         // words of packed state (NN/8)
#define X4N 3125          // WPS/4
#define CEDGE 12800       // edges per chunk in build
#define NCHUNK 500        // CEDGE*NCHUNK == EE
#define PCAP 13312        // p4 half-bucket LDS stage cap

// barrier layout in words (each line 64B apart)
#define BLINES 25         // arrival lines (10 blocks each)
#define BAR_ARR(i) ((i) * 16)
#define BAR_TOP    800
#define BAR_REL(i) (832 + (i) * 16)
#define BAR_WORDS  2048   // 8KB

typedef uint32_t u32x4 __attribute__((ext_vector_type(4)));

// ---------- decode: zero barrier + nextT table + packed state (no atomics) ----------
__global__ void decode_kernel(const float* __restrict__ s0,
                              const float* __restrict__ T,
                              uint32_t* __restrict__ gPk0,
                              uint8_t* __restrict__ nextT,
                              uint32_t* __restrict__ bar) {
    int i = blockIdx.x * blockDim.x + threadIdx.x;
    int stride = gridDim.x * blockDim.x;
    for (int j = i; j < BAR_WORDS; j += stride) bar[j] = 0u;
    if (i < NCHARS) {
        const float* row = T + i * 8;
        int t = 0;
        #pragma unroll
        for (int k = 1; k < 8; ++k) if (row[k] > 0.5f) t = k;
        nextT[i] = (uint8_t)t;
    }
    for (int j = i; j < WPS; j += stride) {
        uint32_t wv = 0;
        const float* rows = s0 + (size_t)j * 64;          // 8 nodes x 8 states
        #pragma unroll
        for (int k = 0; k < 8; ++k) {
            const float* row = rows + k * 8;
            int s = 0;
            #pragma unroll
            for (int q = 1; q < 8; ++q) if (row[q] > 0.5f) s = q;
            wv |= (uint32_t)s << (k << 2);
        }
        gPk0[j] = wv;
    }
}

// ---------- P1: per-chunk bucket histogram (per-wave sub-hists) ----------
__global__ void __launch_bounds__(512) p1_hist(const int* __restrict__ dst,
                                               uint32_t* __restrict__ hist) {
    __shared__ uint32_t cw[8][256];         // 8 KB
    int t = threadIdx.x, w = t >> 6;
    int c = blockIdx.x;
    for (int i = t; i < 8 * 256; i += 512) ((uint32_t*)cw)[i] = 0;
    __syncthreads();
    const int4* p = (const int4*)(dst + c * CEDGE);
    for (int i = t; i < CEDGE / 4; i += 512) {
        int4 d = p[i];
        atomicAdd(&cw[w][d.x / NPB], 1u);
        atomicAdd(&cw[w][d.y / NPB], 1u);
        atomicAdd(&cw[w][d.z / NPB], 1u);
        atomicAdd(&cw[w][d.w / NPB], 1u);
    }
    __syncthreads();
    for (int b = t; b < NBKT; b += 512) {
        uint32_t s = 0;
        #pragma unroll
        for (int w2 = 0; w2 < 8; ++w2) s += cw[w2][b];
        hist[(size_t)c * NBKT + b] = s;
    }
}

// ---------- P2a: per-bucket exclusive scan over chunks ----------
__global__ void p2a_scan(uint32_t* __restrict__ hist, uint32_t* __restrict__ total) {
    __shared__ uint32_t lds[256];
    int t = threadIdx.x;
    int b = blockIdx.x;
    uint32_t carry = 0;
    for (int c0 = 0; c0 < NCHUNK; c0 += 256) {
        int c = c0 + t;
        uint32_t v = (c < NCHUNK) ? hist[(size_t)c * NBKT + b] : 0u;
        lds[t] = v;
        __syncthreads();
        for (int off = 1; off < 256; off <<= 1) {
            uint32_t x = (t >= off) ? lds[t - off] : 0u;
            __syncthreads();
            lds[t] += x;
            __syncthreads();
        }
        if (c < NCHUNK) hist[(size_t)c * NBKT + b] = lds[t] - v + carry;
        uint32_t tot = lds[255];
        __syncthreads();
        carry += tot;
    }
    if (t == 0) total[b] = carry;
}

// ---------- P2b: scan bucket totals ----------
__global__ void p2b_scan(const uint32_t* __restrict__ total,
                         uint32_t* __restrict__ bucket_base) {
    __shared__ uint32_t lds[512];
    int t = threadIdx.x;
    uint32_t v = (t < NBKT) ? total[t] : 0u;
    lds[t] = v;
    __syncthreads();
    for (int off = 1; off < 512; off <<= 1) {
        uint32_t x = (t >= off) ? lds[t - off] : 0u;
        __syncthreads();
        lds[t] += x;
        __syncthreads();
    }
    if (t < NBKT) bucket_base[t] = lds[t] - v;
    if (t == 511) bucket_base[NBKT] = lds[511];   // == EE
}

// ---------- P3: LDS-staged partition, per-wave cursors ----------
__global__ void __launch_bounds__(512) p3_partition(const int* __restrict__ src,
                                                    const int* __restrict__ dst,
                                                    const uint32_t* __restrict__ hist,
                                                    const uint32_t* __restrict__ bucket_base,
                                                    uint32_t* __restrict__ csr) {
    __shared__ uint32_t stage[CEDGE];       // 51.2 KB
    __shared__ uint32_t cw[8][256];         // 8 KB: per-wave counts -> cursors
    __shared__ uint32_t loc[NBKT + 1];
    __shared__ uint32_t segoff[NBKT];
    __shared__ uint32_t scanb[512];
    int t = threadIdx.x, w = t >> 6;
    int c = blockIdx.x;
    int e0 = c * CEDGE;
    const int4* ps4 = (const int4*)(src + e0);
    const int4* pd4 = (const int4*)(dst + e0);
    for (int i = t; i < 8 * 256; i += 512) ((uint32_t*)cw)[i] = 0;
    __syncthreads();
    // count phase: int4 groups; edge group 4i..4i+3 -> wave (i%512)>>6
    for (int i = t; i < CEDGE / 4; i += 512) {
        int4 d = pd4[i];
        atomicAdd(&cw[w][d.x / NPB], 1u);
        atomicAdd(&cw[w][d.y / NPB], 1u);
        atomicAdd(&cw[w][d.z / NPB], 1u);
        atomicAdd(&cw[w][d.w / NPB], 1u);
    }
    __syncthreads();
    uint32_t tot = 0;
    if (t < NBKT) {
        #pragma unroll
        for (int w2 = 0; w2 < 8; ++w2) tot += cw[w2][t];
    }
    scanb[t] = tot;
    __syncthreads();
    for (int off = 1; off < 512; off <<= 1) {
        uint32_t x = (t >= off) ? scanb[t - off] : 0u;
        __syncthreads();
        scanb[t] += x;
        __syncthreads();
    }
    if (t < NBKT) {
        uint32_t excl = scanb[t] - tot;
        loc[t] = excl;
        segoff[t] = bucket_base[t] + hist[(size_t)c * NBKT + t] - excl;
        uint32_t acc = excl;                 // convert counts -> per-wave cursors
        #pragma unroll
        for (int w2 = 0; w2 < 8; ++w2) {
            uint32_t cv = cw[w2][t];
            cw[w2][t] = acc;
            acc += cv;
        }
    }
    if (t == 0) loc[NBKT] = CEDGE;
    __syncthreads();
    // scatter phase: IDENTICAL int4-group mapping (same wave per edge group)
    for (int i = t; i < CEDGE / 4; i += 512) {
        int4 d = pd4[i];
        int4 s = ps4[i];
        int bb; uint32_t dl, pos;
        bb = d.x / NPB; dl = (uint32_t)(d.x - bb * NPB);
        pos = atomicAdd(&cw[w][bb], 1u); stage[pos] = ((uint32_t)s.x << 9) | dl;
        bb = d.y / NPB; dl = (uint32_t)(d.y - bb * NPB);
        pos = atomicAdd(&cw[w][bb], 1u); stage[pos] = ((uint32_t)s.y << 9) | dl;
        bb = d.z / NPB; dl = (uint32_t)(d.z - bb * NPB);
        pos = atomicAdd(&cw[w][bb], 1u); stage[pos] = ((uint32_t)s.z << 9) | dl;
        bb = d.w / NPB; dl = (uint32_t)(d.w - bb * NPB);
        pos = atomicAdd(&cw[w][bb], 1u); stage[pos] = ((uint32_t)s.w << 9) | dl;
    }
    __syncthreads();
    for (int i = t; i < CEDGE; i += 512) {
        int lo = 0, hi = NBKT;                            // loc[lo] <= i < loc[lo+1]
        while (hi - lo > 1) { int mid = (lo + hi) >> 1; if (loc[mid] <= (uint32_t)i) lo = mid; else hi = mid; }
        csr[segoff[lo] + (uint32_t)i] = stage[i];         // consecutive i -> consecutive addr
    }
}

// ---------- P4: bin-sort each half-bucket by src>>8 (gather locality) ----------
__global__ void __launch_bounds__(512) p4_sortsrc(uint32_t* __restrict__ csr,
                                                  const uint32_t* __restrict__ bucket_base) {
    __shared__ uint32_t st[PCAP];           // 53.2 KB
    __shared__ uint32_t binh[512];
    int t = threadIdx.x;
    int j = blockIdx.x;
    int b = j >> 1, h = j & 1;
    uint32_t base = bucket_base[b], endb = bucket_base[b + 1];
    uint32_t n = endb - base;
    uint32_t n1 = (n + 1) >> 1;
    uint32_t r0 = h ? base + n1 : base;
    uint32_t cnt = h ? n - n1 : n1;
    if (cnt > PCAP) return;                 // leave unsorted (still correct)
    for (uint32_t i = t; i < cnt; i += 512) st[i] = csr[r0 + i];
    binh[t] = 0;
    __syncthreads();
    for (uint32_t i = t; i < cnt; i += 512) atomicAdd(&binh[st[i] >> 17], 1u);  // src>>8
    __syncthreads();
    uint32_t v = binh[t];
    __syncthreads();
    for (int off = 1; off < 512; off <<= 1) {
        uint32_t x = (t >= off) ? binh[t - off] : 0u;
        __syncthreads();
        binh[t] += x;
        __syncthreads();
    }
    uint32_t excl = binh[t] - v;
    __syncthreads();
    binh[t] = excl;                          // becomes cursor
    __syncthreads();
    for (uint32_t i = t; i < cnt; i += 512) {
        uint32_t w = st[i];
        uint32_t pos = atomicAdd(&binh[w >> 17], 1u);
        csr[r0 + pos] = w;
    }
}

// ---------- mega: fence-free persistent 20 iterations (unchanged from R9) ----------
__global__ void __launch_bounds__(1024) mega_kernel(const uint32_t* __restrict__ csr,
                                                    const uint32_t* __restrict__ bucket_base,
                                                    uint32_t* __restrict__ gPkA,
                                                    uint32_t* __restrict__ gPkB,
                                                    const uint8_t* __restrict__ nextT,
                                                    float* __restrict__ out,
                                                    uint32_t* __restrict__ bar) {
    __shared__ uint32_t sPk[WPS];           // 50 KB packed state
    __shared__ uint32_t mask[NPB];          // 1.6 KB
    __shared__ uint32_t packOwn[NPB / 8];
    __shared__ uint8_t  nT[NCHARS];
    __shared__ uint8_t  sown[NPB];
    int t = threadIdx.x;
    int b = blockIdx.x;
    uint32_t base = bucket_base[b];
    uint32_t end  = bucket_base[b + 1];

    if (t < 512) ((uint32_t*)nT)[t] = ((const uint32_t*)nextT)[t];   // 2048 B
    const int line = b % BLINES;

    for (int p = 0; p < ITERS; ++p) {
        const uint32_t* curG = (p & 1) ? gPkB : gPkA;
        uint32_t*       nxtG = (p & 1) ? gPkA : gPkB;
        // coherent x4 reload of full packed state (bypasses stale L1/L2)
        {
            const u32x4* g4 = (const u32x4*)curG;
            int i0 = t, i1 = t + 1024, i2 = t + 2048;
            int i3 = t + 3072; if (i3 > X4N - 1) i3 = X4N - 1;
            const u32x4 *p0 = g4 + i0, *p1 = g4 + i1, *p2 = g4 + i2, *p3 = g4 + i3;
            u32x4 a0, a1, a2, a3;
            asm volatile(
                "global_load_dwordx4 %0, %4, off sc1\n\t"
                "global_load_dwordx4 %1, %5, off sc1\n\t"
                "global_load_dwordx4 %2, %6, off sc1\n\t"
                "global_load_dwordx4 %3, %7, off sc1\n\t"
                "s_waitcnt vmcnt(0)"
                : "=&v"(a0), "=&v"(a1), "=&v"(a2), "=&v"(a3)
                : "v"(p0), "v"(p1), "v"(p2), "v"(p3)
                : "memory");
            u32x4* s4 = (u32x4*)sPk;
            s4[i0] = a0; s4[i1] = a1; s4[i2] = a2; s4[i3] = a3;
        }
        if (t < NPB) mask[t] = 0;
        if (t < NPB / 8) packOwn[t] = 0;
        __syncthreads();

        // gather: edges from global (L2-resident, src-sorted), state from LDS
        uint32_t e = base + t;
        for (; e + 3072 < end; e += 4096) {
            uint32_t w0 = csr[e], w1 = csr[e + 1024], w2 = csr[e + 2048], w3 = csr[e + 3072];
            uint32_t s0_ = w0 >> 9, s1_ = w1 >> 9, s2_ = w2 >> 9, s3_ = w3 >> 9;
            uint32_t n0 = (sPk[s0_ >> 3] >> ((s0_ & 7) << 2)) & 7u;
            uint32_t n1 = (sPk[s1_ >> 3] >> ((s1_ & 7) << 2)) & 7u;
            uint32_t n2 = (sPk[s2_ >> 3] >> ((s2_ & 7) << 2)) & 7u;
            uint32_t n3 = (sPk[s3_ >> 3] >> ((s3_ & 7) << 2)) & 7u;
            atomicOr(&mask[w0 & 511u], 1u << n0);
            atomicOr(&mask[w1 & 511u], 1u << n1);
            atomicOr(&mask[w2 & 511u], 1u << n2);
            atomicOr(&mask[w3 & 511u], 1u << n3);
        }
        for (; e < end; e += 1024) {
            uint32_t w = csr[e];
            uint32_t s_ = w >> 9;
            uint32_t nb = (sPk[s_ >> 3] >> ((s_ & 7) << 2)) & 7u;
            atomicOr(&mask[w & 511u], 1u << nb);
        }
        __syncthreads();

        // own-node update + nibble pack
        if (t < NPB) {
            int node = b * NPB + t;
            uint32_t sOwn = (sPk[node >> 3] >> ((node & 7) << 2)) & 7u;
            uint8_t ns = nT[(mask[t] << 3) + sOwn];
            sown[t] = ns;
            atomicOr(&packOwn[t >> 3], (uint32_t)ns << ((t & 7) << 2));
        }
        __syncthreads();
        if (p < ITERS - 1) {
            if (t < NPB / 8)
                __hip_atomic_store(&nxtG[(NPB / 8) * b + t], packOwn[t],
                                   __ATOMIC_RELAXED, __HIP_MEMORY_SCOPE_AGENT);
            __syncthreads();                 // drains vmcnt: stores at coherence point
            if (t == 0) {
                uint32_t epoch = (uint32_t)(p + 1);
                uint32_t old = atomicAdd(&bar[BAR_ARR(line)], 1u);
                if (old + 1u == 10u * epoch) {             // group complete
                    uint32_t told = atomicAdd(&bar[BAR_TOP], 1u);
                    if (told + 1u == (uint32_t)BLINES * epoch) {   // all arrived
                        for (int r = 0; r < BLINES; ++r)
                            atomicExch(&bar[BAR_REL(r)], epoch);   // fan-out release
                    }
                }
                while (__hip_atomic_load(&bar[BAR_REL(line)], __ATOMIC_RELAXED,
                                         __HIP_MEMORY_SCOPE_AGENT) < epoch)
                    __builtin_amdgcn_s_sleep(16);
            }
            __syncthreads();
        }
    }
    __syncthreads();
    // one-hot output: 400 nodes * 8 floats, coalesced
    for (int f = t; f < NPB * 8; f += 1024) {
        int node = f >> 3;
        out[(size_t)b * (NPB * 8) + f] = ((f & 7) == (int)sown[node]) ? 1.f : 0.f;
    }
}

// ---------- fallback (tiny ws): R1 mask/atomicOr path ----------
__global__ void fb_decode(const float* __restrict__ s0, const float* __restrict__ T,
                          uint8_t* __restrict__ state, uint8_t* __restrict__ nextT,
                          uint32_t* __restrict__ mask) {
    int i = blockIdx.x * blockDim.x + threadIdx.x;
    if (i < NCHARS) {
        const float* row = T + i * 8;
        int t = 0;
        #pragma unroll
        for (int k = 1; k < 8; ++k) if (row[k] > 0.5f) t = k;
        nextT[i] = (uint8_t)t;
    }
    if (i < NN) {
        const float* row = s0 + i * 8;
        int s = 0;
        #pragma unroll
        for (int k = 1; k < 8; ++k) if (row[k] > 0.5f) s = k;
        state[i] = (uint8_t)s;
        mask[i] = 0u;
    }
}
__global__ void fb_edge(const int* __restrict__ src, const int* __restrict__ dst,
                        const uint8_t* __restrict__ state, uint32_t* __restrict__ mask) {
    int i = blockIdx.x * blockDim.x + threadIdx.x;
    int stride = gridDim.x * blockDim.x;
    for (int e = i; e < EE; e += stride) atomicOr(&mask[dst[e]], 1u << state[src[e]]);
}
__global__ void fb_update(uint8_t* __restrict__ state, uint32_t* __restrict__ mask,
                          const uint8_t* __restrict__ nextT) {
    int i = blockIdx.x * blockDim.x + threadIdx.x;
    if (i < NN) {
        uint32_t m = mask[i];
        state[i] = nextT[(m << 3) + state[i]];
        mask[i] = 0u;
    }
}
__global__ void fb_output(const uint8_t* __restrict__ state, float* __restrict__ out) {
    int i = blockIdx.x * blockDim.x + threadIdx.x;
    if (i < NN) {
        int s = state[i];
        float4 lo = make_float4(s == 0 ? 1.f : 0.f, s == 1 ? 1.f : 0.f,
                                s == 2 ? 1.f : 0.f, s == 3 ? 1.f : 0.f);
        float4 hi = make_float4(s == 4 ? 1.f : 0.f, s == 5 ? 1.f : 0.f,
                                s == 6 ? 1.f : 0.f, s == 7 ? 1.f : 0.f);
        float4* o = (float4*)(out + (size_t)i * 8);
        o[0] = lo;
        o[1] = hi;
    }
}

extern "C" void kernel_launch(void* const* d_in, const int* in_sizes, int n_in,
                              void* d_out, int out_size, void* d_ws, size_t ws_size,
                              hipStream_t stream) {
    const float* s0  = (const float*)d_in[0];
    const int*   ei  = (const int*)d_in[1];   // [2,E]: row0=src, row1=dst
    const float* T   = (const float*)d_in[2];
    float*       out = (float*)d_out;
    const int* src = ei;
    const int* dst = ei + EE;

    uint8_t* basep = (uint8_t*)d_ws;
    size_t off = 0;
    auto alloc = [&](size_t sz) -> void* {
        void* p = basep + off;
        off += (sz + 255) & ~(size_t)255;
        return p;
    };
    uint32_t* csr         = (uint32_t*)alloc(sizeof(uint32_t) * EE);
    uint32_t* hist        = (uint32_t*)alloc(sizeof(uint32_t) * (size_t)NCHUNK * NBKT);
    uint32_t* total       = (uint32_t*)alloc(sizeof(uint32_t) * NBKT);
    uint32_t* bucket_base = (uint32_t*)alloc(sizeof(uint32_t) * (NBKT + 1));
    uint8_t*  nextT       = (uint8_t*)alloc(NCHARS);
    uint32_t* gPkA        = (uint32_t*)alloc(sizeof(uint32_t) * WPS);
    uint32_t* gPkB        = (uint32_t*)alloc(sizeof(uint32_t) * WPS);
    uint32_t* bar         = (uint32_t*)alloc(sizeof(uint32_t) * BAR_WORDS);
    bool have_ws = (off <= ws_size);

    if (have_ws) {
        decode_kernel<<<51, 256, 0, stream>>>(s0, T, gPkA, nextT, bar);
        p1_hist<<<NCHUNK, 512, 0, stream>>>(dst, hist);
        p2a_scan<<<NBKT, 256, 0, stream>>>(hist, total);
        p2b_scan<<<1, 512, 0, stream>>>(total, bucket_base);
        p3_partition<<<NCHUNK, 512, 0, stream>>>(src, dst, hist, bucket_base, csr);
        p4_sortsrc<<<NBKT * 2, 512, 0, stream>>>(csr, bucket_base);
        mega_kernel<<<NBKT, 1024, 0, stream>>>(csr, bucket_base, gPkA, gPkB,
                                               nextT, out, bar);
    } else {
        uint32_t* mask = (uint32_t*)d_ws;           // < 1 MB path
        uint8_t*  nT   = (uint8_t*)d_ws + 400128;
        uint8_t*  st   = (uint8_t*)d_ws + 402432;
        fb_decode<<<391, 256, 0, stream>>>(s0, T, st, nT, mask);
        for (int it = 0; it < ITERS; ++it) {
            fb_edge<<<2048, 256, 0, stream>>>(src, dst, st, mask);
            fb_update<<<391, 256, 0, stream>>>(st, mask, nT);
        }
        fb_output<<<391, 256, 0, stream>>>(st, out);
    }
}